// Round 5
// baseline (58.224 us; speedup 1.0000x reference)
//
#include <hip/hip_runtime.h>
#include <math.h>

// ElasticSparseAttention: B=1, H=16, KVH=4, S=2048, D=64, W=64, layer 12/24.
// One wave per TWO rows (h,s) and (h,s+1): two independent dep-chains per
// wave so row B's gathers/dots issue under row A's softmax shfl latency.
// Lane (r,c), r=lane>>2, c=lane&3, owns window slot j=p*16+r across 4 phases;
// quads cover full 64B lines for both K and V gathers. All register arrays
// statically indexed (runtime-indexed ext-vector arrays go to scratch).

#define NH   16
#define SEQ  2048
#define HD   64
#define WIN  64

#define ALPHA_F ((float)(12.0 / 23.0))
#define PD0_F   ((float)(64.0 * (1.0 - 12.0 / 23.0)))
#define NEG_MIN (-3.4028234663852886e38f)

__device__ __forceinline__ void elastic_params(int s, int* start, float* spacing)
{
    const int   end     = (s > WIN - 1) ? s : (WIN - 1);
    const float ids_len = (float)(end + 1);
    const float pd      = __fadd_rn(PD0_F, __fmul_rn(ids_len, ALPHA_F));
    float start_f       = rintf(__fsub_rn(ids_len, pd));
    if (start_f < 0.0f) start_f = 0.0f;
    const int   st      = (int)start_f;
    const float window  = (float)(end + 1 - st);
    *start   = st;
    *spacing = __fmul_rn(window, 0.015625f);   // /64 exact
}

__device__ __forceinline__ int elastic_idx(int j, int start, float spacing,
                                           float omiw, float iw, int s, bool* valid)
{
    const int rel0 = (int)rintf(__fmul_rn((float)j, spacing));
    const int rel1 = (int)rintf(__fmul_rn((float)(j + 1), spacing));
    const int basej    = start + rel0;
    const int shiftedj = start + rel1 - 1;
    const float idxf = __fadd_rn(__fmul_rn((float)basej, omiw),
                                 __fmul_rn((float)shiftedj, iw));
    int idx = (int)rintf(idxf);
    *valid = (idx <= s);
    return *valid ? idx : 0;
}

__global__ __launch_bounds__(256) void esa_kernel(
    const float* __restrict__ q,
    const float* __restrict__ k,
    const float* __restrict__ v,
    float* __restrict__ out)
{
    const int lane = threadIdx.x & 63;
    const int wid  = threadIdx.x >> 6;
    const int base = (blockIdx.x * 4 + wid) * 2;   // two (h,s) pairs per wave
    const int h    = base >> 11;
    const int s0   = base & (SEQ - 1);             // even
    const int s1   = s0 + 1;                       // same h (s0 even)
    const int kvh  = h >> 2;

    const int r = lane >> 2;   // window-slot-within-phase 0..15
    const int c = lane & 3;    // 16B chunk within 64B line 0..3

    int   start0, start1;
    float spacing0, spacing1;
    elastic_params(s0, &start0, &spacing0);
    elastic_params(s1, &start1, &spacing1);
    const float iw   = __fdiv_rn((float)h, 15.0f);
    const float omiw = __fsub_rn(1.0f, iw);

    // q fragments straight from global: instr i touches one 64B line of the row
    const float4* qrow0 = (const float4*)(q + (size_t)(h * SEQ + s0) * HD);
    const float4* qrow1 = (const float4*)(q + (size_t)(h * SEQ + s1) * HD);
    float4 qq0[4], qq1[4];
    #pragma unroll
    for (int i = 0; i < 4; ++i) { qq0[i] = qrow0[4 * i + c]; qq1[i] = qrow1[4 * i + c]; }

    const float* kbase = k + (size_t)kvh * SEQ * HD;
    const float* vbase = v + (size_t)kvh * SEQ * HD;

    // ---- QK: both rows interleaved; quad-per-K-row coalesced gather ----
    float sc0[4], sc1[4];
    int   idx0[4], idx1[4];
    #pragma unroll
    for (int p = 0; p < 4; ++p) {
        const int j = p * 16 + r;
        bool va0, va1;
        idx0[p] = elastic_idx(j, start0, spacing0, omiw, iw, s0, &va0);
        idx1[p] = elastic_idx(j, start1, spacing1, omiw, iw, s1, &va1);

        const float4* krow0 = (const float4*)(kbase + (size_t)idx0[p] * HD);
        const float4* krow1 = (const float4*)(kbase + (size_t)idx1[p] * HD);
        float d0 = 0.0f, d1 = 0.0f;
        #pragma unroll
        for (int i = 0; i < 4; ++i) {
            float4 ka = krow0[4 * i + c];
            float4 kb = krow1[4 * i + c];
            d0 += qq0[i].x * ka.x + qq0[i].y * ka.y + qq0[i].z * ka.z + qq0[i].w * ka.w;
            d1 += qq1[i].x * kb.x + qq1[i].y * kb.y + qq1[i].z * kb.z + qq1[i].w * kb.w;
        }
        d0 += __shfl_xor(d0, 1); d0 += __shfl_xor(d0, 2);
        d1 += __shfl_xor(d1, 1); d1 += __shfl_xor(d1, 2);
        sc0[p] = va0 ? d0 * 0.125f : NEG_MIN;
        sc1[p] = va1 ? d1 * 0.125f : NEG_MIN;
    }

    // ---- softmax, two independent chains interleaved ----
    float m0 = fmaxf(fmaxf(sc0[0], sc0[1]), fmaxf(sc0[2], sc0[3]));
    float m1 = fmaxf(fmaxf(sc1[0], sc1[1]), fmaxf(sc1[2], sc1[3]));
    #pragma unroll
    for (int off = 4; off <= 32; off <<= 1) {
        m0 = fmaxf(m0, __shfl_xor(m0, off));
        m1 = fmaxf(m1, __shfl_xor(m1, off));
    }
    float e0[4], e1[4], ssum0 = 0.0f, ssum1 = 0.0f;
    #pragma unroll
    for (int p = 0; p < 4; ++p) {
        e0[p] = __expf(sc0[p] - m0); ssum0 += e0[p];
        e1[p] = __expf(sc1[p] - m1); ssum1 += e1[p];
    }
    #pragma unroll
    for (int off = 4; off <= 32; off <<= 1) {
        ssum0 += __shfl_xor(ssum0, off);
        ssum1 += __shfl_xor(ssum1, off);
    }

    // ---- PV: e/idx lane-local; both rows' gathers interleaved ----
    float4 acc0[4], acc1[4];
    #pragma unroll
    for (int i = 0; i < 4; ++i) {
        acc0[i] = make_float4(0.f, 0.f, 0.f, 0.f);
        acc1[i] = make_float4(0.f, 0.f, 0.f, 0.f);
    }
    #pragma unroll
    for (int p = 0; p < 4; ++p) {
        const float4* vrow0 = (const float4*)(vbase + (size_t)idx0[p] * HD);
        const float4* vrow1 = (const float4*)(vbase + (size_t)idx1[p] * HD);
        const float ea = e0[p], eb = e1[p];     // 0 for masked slots
        #pragma unroll
        for (int i = 0; i < 4; ++i) {
            float4 va = vrow0[4 * i + c];
            float4 vb = vrow1[4 * i + c];
            acc0[i].x += ea * va.x; acc0[i].y += ea * va.y;
            acc0[i].z += ea * va.z; acc0[i].w += ea * va.w;
            acc1[i].x += eb * vb.x; acc1[i].y += eb * vb.y;
            acc1[i].z += eb * vb.z; acc1[i].w += eb * vb.w;
        }
    }

    // full reduce across the 16 r-lanes (bits 2..5); static indices only
    #pragma unroll
    for (int off = 4; off <= 32; off <<= 1) {
        #pragma unroll
        for (int i = 0; i < 4; ++i) {
            acc0[i].x += __shfl_xor(acc0[i].x, off);
            acc0[i].y += __shfl_xor(acc0[i].y, off);
            acc0[i].z += __shfl_xor(acc0[i].z, off);
            acc0[i].w += __shfl_xor(acc0[i].w, off);
            acc1[i].x += __shfl_xor(acc1[i].x, off);
            acc1[i].y += __shfl_xor(acc1[i].y, off);
            acc1[i].z += __shfl_xor(acc1[i].z, off);
            acc1[i].w += __shfl_xor(acc1[i].w, off);
        }
    }

    // lanes 0..3 store row0, lanes 4..7 store row1 (register cndmask selects,
    // static acc indices -> no scratch)
    if (lane < 8) {
        const bool row1sel = lane >= 4;
        const float inv = 1.0f / (row1sel ? ssum1 : ssum0);
        float4* orow = (float4*)(out + (size_t)(h * SEQ + (row1sel ? s1 : s0)) * HD);
        #pragma unroll
        for (int i = 0; i < 4; ++i) {
            float4 o;
            o.x = row1sel ? acc1[i].x : acc0[i].x;
            o.y = row1sel ? acc1[i].y : acc0[i].y;
            o.z = row1sel ? acc1[i].z : acc0[i].z;
            o.w = row1sel ? acc1[i].w : acc0[i].w;
            o.x *= inv; o.y *= inv; o.z *= inv; o.w *= inv;
            orow[4 * i + c] = o;
        }
    }
}

extern "C" void kernel_launch(void* const* d_in, const int* in_sizes, int n_in,
                              void* d_out, int out_size, void* d_ws, size_t ws_size,
                              hipStream_t stream) {
    const float* q = (const float*)d_in[0];
    const float* k = (const float*)d_in[1];
    const float* v = (const float*)d_in[2];
    float* out = (float*)d_out;
    const int nblocks = NH * SEQ / 8;   // 4 waves/block, two (h,s) per wave
    esa_kernel<<<nblocks, 256, 0, stream>>>(q, k, v, out);
}

// Round 6
// 52.167 us; speedup vs baseline: 1.1161x; 1.1161x over previous
//
#include <hip/hip_runtime.h>
#include <math.h>

// ElasticSparseAttention: B=1, H=16, KVH=4, S=2048, D=64, W=64, layer 12/24.
// One wave per (h,s). Lane (r,c), r=lane>>2, c=lane&3, owns window slot
// j = p*16+r across 4 phases; the 4 lanes of a quad cover one full 64B line
// of each gathered K/V row. Deep prefetch: ALL 16 K lines loaded into regs
// before the dots, ALL 16 V lines issued before the softmax shfl chain so
// DS latency hides VMEM latency. Two latency exposures per wave instead of
// eight. All register arrays statically indexed (runtime indexing -> scratch).

#define NH   16
#define SEQ  2048
#define HD   64
#define WIN  64

// Index-math constants folded in double exactly as Python does, then f32.
#define ALPHA_F ((float)(12.0 / 23.0))
#define PD0_F   ((float)(64.0 * (1.0 - 12.0 / 23.0)))
#define NEG_MIN (-3.4028234663852886e38f)

__global__ __launch_bounds__(256, 4) void esa_kernel(
    const float* __restrict__ q,
    const float* __restrict__ k,
    const float* __restrict__ v,
    float* __restrict__ out)
{
    const int lane = threadIdx.x & 63;
    const int wid  = threadIdx.x >> 6;
    const int pair = blockIdx.x * 4 + wid;   // pair = h*SEQ + s
    const int h    = pair >> 11;
    const int s    = pair & (SEQ - 1);
    const int kvh  = h >> 2;

    const int r = lane >> 2;   // window-slot-within-phase 0..15
    const int c = lane & 3;    // 16B chunk within 64B line, 0..3

    // ---- wave-uniform elastic params (bit-exact f32, no FMA contraction) ----
    const int   end     = (s > WIN - 1) ? s : (WIN - 1);
    const float ids_len = (float)(end + 1);
    const float pd      = __fadd_rn(PD0_F, __fmul_rn(ids_len, ALPHA_F));
    float start_f       = rintf(__fsub_rn(ids_len, pd));
    if (start_f < 0.0f) start_f = 0.0f;
    const int   start   = (int)start_f;
    const float window  = (float)(end + 1 - start);
    const float spacing = __fmul_rn(window, 0.015625f);   // /64 exact
    const float iw      = __fdiv_rn((float)h, 15.0f);
    const float omiw    = __fsub_rn(1.0f, iw);

    // ---- all 4 window indices for this lane's r ----
    int  idxar[4];
    bool valid[4];
    #pragma unroll
    for (int p = 0; p < 4; ++p) {
        const int j    = p * 16 + r;
        const int rel0 = (int)rintf(__fmul_rn((float)j, spacing));
        const int rel1 = (int)rintf(__fmul_rn((float)(j + 1), spacing));
        const int basej    = start + rel0;      // over[:, :W]
        const int shiftedj = start + rel1 - 1;  // over[:, 1:] - 1
        const float idxf = __fadd_rn(__fmul_rn((float)basej, omiw),
                                     __fmul_rn((float)shiftedj, iw));
        int idx = (int)rintf(idxf);
        valid[p] = (idx <= s);
        idxar[p] = valid[p] ? idx : 0;
    }

    // ---- q fragments straight from global (4 broadcast-line loads) ----
    const float4* qrow = (const float4*)(q + (size_t)(h * SEQ + s) * HD);
    float4 qq[4];
    #pragma unroll
    for (int i = 0; i < 4; ++i) qq[i] = qrow[4 * i + c];

    const float* kbase = k + (size_t)kvh * SEQ * HD;
    const float* vbase = v + (size_t)kvh * SEQ * HD;

    // ---- prefetch ALL 16 K lines into registers ----
    float4 kf[4][4];
    #pragma unroll
    for (int p = 0; p < 4; ++p) {
        const float4* krow = (const float4*)(kbase + (size_t)idxar[p] * HD);
        #pragma unroll
        for (int i = 0; i < 4; ++i) kf[p][i] = krow[4 * i + c];
    }

    // ---- dots + quad reduce ----
    float sc[4];
    #pragma unroll
    for (int p = 0; p < 4; ++p) {
        float dot = 0.0f;
        #pragma unroll
        for (int i = 0; i < 4; ++i) {
            dot += qq[i].x * kf[p][i].x + qq[i].y * kf[p][i].y
                 + qq[i].z * kf[p][i].z + qq[i].w * kf[p][i].w;
        }
        dot += __shfl_xor(dot, 1);
        dot += __shfl_xor(dot, 2);
        sc[p] = valid[p] ? dot * 0.125f : NEG_MIN;
    }

    // ---- issue ALL 16 V lines BEFORE the softmax chain (latency overlap) ----
    float4 vf[4][4];
    #pragma unroll
    for (int p = 0; p < 4; ++p) {
        const float4* vrow = (const float4*)(vbase + (size_t)idxar[p] * HD);
        #pragma unroll
        for (int i = 0; i < 4; ++i) vf[p][i] = vrow[4 * i + c];
    }

    // ---- softmax over 64 slots (values replicated x4 across c) ----
    float m = fmaxf(fmaxf(sc[0], sc[1]), fmaxf(sc[2], sc[3]));
    #pragma unroll
    for (int off = 4; off <= 32; off <<= 1) m = fmaxf(m, __shfl_xor(m, off));
    float e[4];
    float ssum = 0.0f;
    #pragma unroll
    for (int p = 0; p < 4; ++p) { e[p] = __expf(sc[p] - m); ssum += e[p]; }
    #pragma unroll
    for (int off = 4; off <= 32; off <<= 1) ssum += __shfl_xor(ssum, off);

    // ---- PV accumulate (V already resident) ----
    float4 acc[4];
    #pragma unroll
    for (int i = 0; i < 4; ++i) acc[i] = make_float4(0.f, 0.f, 0.f, 0.f);
    #pragma unroll
    for (int p = 0; p < 4; ++p) {
        const float ep = e[p];                  // 0 for masked slots
        #pragma unroll
        for (int i = 0; i < 4; ++i) {
            acc[i].x += ep * vf[p][i].x; acc[i].y += ep * vf[p][i].y;
            acc[i].z += ep * vf[p][i].z; acc[i].w += ep * vf[p][i].w;
        }
    }

    // full reduce across the 16 r-lanes (lane bits 2..5); static indices only
    #pragma unroll
    for (int off = 4; off <= 32; off <<= 1) {
        #pragma unroll
        for (int i = 0; i < 4; ++i) {
            acc[i].x += __shfl_xor(acc[i].x, off);
            acc[i].y += __shfl_xor(acc[i].y, off);
            acc[i].z += __shfl_xor(acc[i].z, off);
            acc[i].w += __shfl_xor(acc[i].w, off);
        }
    }

    // lanes 0..3 (c = lane) each store all 4 chunks at orow[4*i + c]:
    // per i, the 4 lanes' float4s form one contiguous 64B line.
    if (lane < 4) {
        const float inv = 1.0f / ssum;
        float4* orow = (float4*)(out + (size_t)(h * SEQ + s) * HD);
        #pragma unroll
        for (int i = 0; i < 4; ++i) {
            float4 o = acc[i];
            o.x *= inv; o.y *= inv; o.z *= inv; o.w *= inv;
            orow[4 * i + lane] = o;
        }
    }
}

extern "C" void kernel_launch(void* const* d_in, const int* in_sizes, int n_in,
                              void* d_out, int out_size, void* d_ws, size_t ws_size,
                              hipStream_t stream) {
    const float* q = (const float*)d_in[0];
    const float* k = (const float*)d_in[1];
    const float* v = (const float*)d_in[2];
    float* out = (float*)d_out;
    const int nblocks = NH * SEQ / 4;   // 4 waves/block, one (h,s) per wave
    esa_kernel<<<nblocks, 256, 0, stream>>>(q, k, v, out);
}